// Round 2
// baseline (166.495 us; speedup 1.0000x reference)
//
#include <hip/hip_runtime.h>
#include <hip/hip_bf16.h>

#define NAG 8
#define BATCH 32768
#define DDIM 128
#define ADIM 64
#define HDIM 128

#define NJ1 11            // layer1 col tiles: 128 (W1) + 32 (Wc1) + 1 (Ws1) -> 176 cols
#define NJ2 8
#define NJ3 4
#define FB_L1 (NJ1*4)     // 44 frag blocks
#define FB_L2 (NJ2*4)     // 32
#define FB_L3 (NJ3*4)     // 16
#define FB_TOT (FB_L1+FB_L2+FB_L3)  // 92
#define WAGENT (FB_TOT*512)         // 47104 ushort per agent (92KB)

typedef __attribute__((ext_vector_type(8))) short bf16x8;
typedef __attribute__((ext_vector_type(4))) float f32x4;
typedef __attribute__((ext_vector_type(4))) unsigned int u32x4;

static __device__ __forceinline__ unsigned short f2bf(float f) {
  unsigned int u = __builtin_bit_cast(unsigned int, f);
  u += 0x7fffu + ((u >> 16) & 1u);          // RNE (inputs are finite)
  return (unsigned short)(u >> 16);
}

static __device__ __forceinline__ unsigned int cvt_pk_bf16(float a, float b) {
  unsigned int r;
  asm("v_cvt_pk_bf16_f32 %0, %1, %2" : "=v"(r) : "v"(a), "v"(b));
  return r;
}

// ---------------- prep: f32 weights -> bf16 B-fragment-linear layout (unchanged, proven) ---------
// frag block fb=(j,kk): 512 bf16; element l*8+t = W[k = kk*32 + (l>>4)*8 + t][col = j*16 + (l&15)]
__global__ void __launch_bounds__(256)
prep_weights(const float* __restrict__ W1, const float* __restrict__ W2,
             const float* __restrict__ W3, const float* __restrict__ Wc1,
             const float* __restrict__ Ws1, const float* __restrict__ b1,
             const float* __restrict__ bc1, const float* __restrict__ bs1,
             unsigned short* __restrict__ wbuf, float* __restrict__ b1e)
{
  int tid = blockIdx.x * 256 + threadIdx.x;
  if (tid < NAG * WAGENT) {
    int agent = tid / WAGENT;
    int rem   = tid % WAGENT;
    int fb = rem >> 9;
    int li = rem & 511;
    int l = li >> 3, t = li & 7;
    int lr = l & 15, lg = l >> 4;
    float v = 0.0f;
    if (fb < FB_L1) {
      int j = fb >> 2, kk = fb & 3;
      int col = j*16 + lr, k = kk*32 + lg*8 + t;
      if (col < 128)       v = W1[((size_t)agent*128 + k)*128 + col];
      else if (col < 160)  v = Wc1[k*32 + (col-128)];
      else if (col == 160) v = Ws1[k];
    } else if (fb < FB_L1 + FB_L2) {
      int f = fb - FB_L1;
      int j = f >> 2, kk = f & 3;
      int col = j*16 + lr, k = kk*32 + lg*8 + t;
      v = W2[((size_t)agent*128 + k)*128 + col];
    } else {
      int f = fb - FB_L1 - FB_L2;
      int j = f >> 2, kk = f & 3;
      int col = j*16 + lr, k = kk*32 + lg*8 + t;
      v = W3[((size_t)agent*128 + k)*64 + col];
    }
    wbuf[tid] = f2bf(v);
  }
  if (tid < NAG * 176) {     // extended layer-1 bias: [b1 | bc1 | bs1 | 0]
    int agent = tid / 176, col = tid % 176;
    float v = 0.0f;
    if (col < 128)       v = b1[agent*128 + col];
    else if (col < 160)  v = bc1[col - 128];
    else if (col == 160) v = bs1[0];
    b1e[tid] = v;
  }
}

// ---------------- main: agent-parallel waves ----------------
// 512 threads = 8 waves; wave w handles agent w for this block's 128 rows,
// in 2 passes of M=64. Weights read straight from global (L2-resident).
// LDS: per-wave 16KB h buffer; reused as f32 partial for cross-agent reduce.
__global__ void __launch_bounds__(512, 2)
qatten_main(const float* __restrict__ states,
            const float* __restrict__ b2g, const float* __restrict__ b3g,
            const float* __restrict__ ws2p, const float* __restrict__ bs2p,
            const float* __restrict__ wc2g, const float* __restrict__ bc2p,
            const unsigned short* __restrict__ wbuf,
            const float* __restrict__ b1e,
            float* __restrict__ out)
{
  __shared__ __align__(16) unsigned short hlds[8 * 8192];   // 128 KB total

  const int tid  = threadIdx.x;
  const int wave = tid >> 6;
  const int lane = tid & 63;
  const int lr   = lane & 15;
  const int lg   = lane >> 4;
  const int agent = wave;

  const unsigned short* wag = wbuf + (size_t)agent * WAGENT;
  unsigned short* hp = hlds + wave * 8192;          // this wave's 16KB region

  // per-wave (per-agent) constants
  float b1v[NJ1], b2v[NJ2], b3v[NJ3];
#pragma unroll
  for (int j = 0; j < NJ1; ++j) b1v[j] = b1e[agent*176 + j*16 + lr];
#pragma unroll
  for (int j = 0; j < NJ2; ++j) b2v[j] = b2g[agent*HDIM + j*16 + lr];
#pragma unroll
  for (int j = 0; j < NJ3; ++j) b3v[j] = b3g[agent*ADIM + j*16 + lr];
  const float ws2  = ws2p[0];
  const float bs2v = bs2p[0];
  const float bc2v = bc2p[0];
  const float wc2a = wc2g[lr];
  const float wc2b = wc2g[16 + lr];

  const f32x4 zero4 = {0.f, 0.f, 0.f, 0.f};

  for (int pass = 0; pass < 2; ++pass) {
    const int row0 = blockIdx.x * 128 + pass * 64;

    // ---- A1 fragments from global states (f32 -> bf16, 4 m-tiles) ----
    bf16x8 afr[4][4];
    {
      const float* sb = states + ((size_t)agent * BATCH + row0) * DDIM;
#pragma unroll
      for (int m = 0; m < 4; ++m)
#pragma unroll
        for (int kk = 0; kk < 4; ++kk) {
          const float* p = sb + (m*16 + lr)*DDIM + kk*32 + lg*8;
          f32x4 v0 = *(const f32x4*)p;
          f32x4 v1 = *(const f32x4*)(p + 4);
          u32x4 w;
          w[0] = cvt_pk_bf16(v0[0], v0[1]);
          w[1] = cvt_pk_bf16(v0[2], v0[3]);
          w[2] = cvt_pk_bf16(v1[0], v1[1]);
          w[3] = cvt_pk_bf16(v1[2], v1[3]);
          afr[m][kk] = __builtin_bit_cast(bf16x8, w);
        }
    }

    // ---- gate & constraint tiles first (j = 8,9,10), then free the regs ----
    float scl[4][4], crow[4][4];
    {
      f32x4 eacc[3][4];
#pragma unroll
      for (int jx = 0; jx < 3; ++jx) {
        bf16x8 bfr[4];
#pragma unroll
        for (int kk = 0; kk < 4; ++kk)
          bfr[kk] = *(const bf16x8*)&wag[((8+jx)*4 + kk)*512 + lane*8];
#pragma unroll
        for (int m = 0; m < 4; ++m) {
          f32x4 a = zero4;
#pragma unroll
          for (int kk = 0; kk < 4; ++kk)
            a = __builtin_amdgcn_mfma_f32_16x16x32_bf16(afr[m][kk], bfr[kk], a, 0, 0, 0);
          eacc[jx][m] = a;
        }
      }
#pragma unroll
      for (int m = 0; m < 4; ++m) {
#pragma unroll
        for (int r = 0; r < 4; ++r) {
          float c0 = eacc[0][m][r] + b1v[8];  c0 = c0 > 0.f ? c0 : 0.f;
          float c1 = eacc[1][m][r] + b1v[9];  c1 = c1 > 0.f ? c1 : 0.f;
          float cd = c0*wc2a + c1*wc2b;
          cd += __shfl_xor(cd, 1);
          cd += __shfl_xor(cd, 2);
          cd += __shfl_xor(cd, 4);
          cd += __shfl_xor(cd, 8);          // sum over 16 cols within lg-group
          crow[m][r] = cd + bc2v;
          float sp = eacc[2][m][r] + b1v[10];
          sp = __shfl(sp, lane & 48);       // broadcast col-160 (lr==0) value
          sp = sp > 0.f ? sp : 0.f;
          float s = ws2 * sp + bs2v;
          scl[m][r] = 1.f / (1.f + __expf(-s));
        }
      }
    }

    // ---- layer 1 main (j = 0..7) -> h (swizzled row-major [64][128] bf16) ----
#pragma unroll
    for (int j = 0; j < 8; ++j) {
      bf16x8 bfr[4];
#pragma unroll
      for (int kk = 0; kk < 4; ++kk)
        bfr[kk] = *(const bf16x8*)&wag[(j*4 + kk)*512 + lane*8];
#pragma unroll
      for (int m = 0; m < 4; ++m) {
        f32x4 acc = zero4;
#pragma unroll
        for (int kk = 0; kk < 4; ++kk)
          acc = __builtin_amdgcn_mfma_f32_16x16x32_bf16(afr[m][kk], bfr[kk], acc, 0, 0, 0);
#pragma unroll
        for (int r = 0; r < 4; ++r) {
          float hv = acc[r] + b1v[j];
          hv = hv > 0.f ? hv : 0.f;
          int row = m*16 + lg*4 + r;
          int bo = row*256 + (((j*16 + lr)*2) ^ ((row & 7) << 4));   // XOR swizzle
          *(unsigned short*)((char*)hp + bo) = f2bf(hv);
        }
      }
    }

    asm volatile("s_waitcnt lgkmcnt(0)" ::: "memory");
    // ---- A2 fragments from own h region ----
#pragma unroll
    for (int m = 0; m < 4; ++m)
#pragma unroll
      for (int kk = 0; kk < 4; ++kk) {
        int row = m*16 + lr;
        int bo = row*256 + ((kk*64 + lg*16) ^ ((row & 7) << 4));
        afr[m][kk] = *(const bf16x8*)((char*)hp + bo);
      }

    // ---- layer 2 (j = 0..7) ----
#pragma unroll
    for (int j = 0; j < 8; ++j) {
      bf16x8 bfr[4];
#pragma unroll
      for (int kk = 0; kk < 4; ++kk)
        bfr[kk] = *(const bf16x8*)&wag[(FB_L1 + j*4 + kk)*512 + lane*8];
#pragma unroll
      for (int m = 0; m < 4; ++m) {
        f32x4 acc = zero4;
#pragma unroll
        for (int kk = 0; kk < 4; ++kk)
          acc = __builtin_amdgcn_mfma_f32_16x16x32_bf16(afr[m][kk], bfr[kk], acc, 0, 0, 0);
#pragma unroll
        for (int r = 0; r < 4; ++r) {
          float hv = acc[r] + b2v[j];
          hv = hv > 0.f ? hv : 0.f;
          int row = m*16 + lg*4 + r;
          int bo = row*256 + (((j*16 + lr)*2) ^ ((row & 7) << 4));
          *(unsigned short*)((char*)hp + bo) = f2bf(hv);   // overwrite h1
        }
      }
    }

    asm volatile("s_waitcnt lgkmcnt(0)" ::: "memory");
    // ---- A3 fragments from h2 ----
#pragma unroll
    for (int m = 0; m < 4; ++m)
#pragma unroll
      for (int kk = 0; kk < 4; ++kk) {
        int row = m*16 + lr;
        int bo = row*256 + ((kk*64 + lg*16) ^ ((row & 7) << 4));
        afr[m][kk] = *(const bf16x8*)((char*)hp + bo);
      }

    // ---- layer 3 (q), gated, + c folded in ----
    f32x4 out_acc[4][NJ3];
#pragma unroll
    for (int j = 0; j < NJ3; ++j) {
      bf16x8 bfr[4];
#pragma unroll
      for (int kk = 0; kk < 4; ++kk)
        bfr[kk] = *(const bf16x8*)&wag[(FB_L1 + FB_L2 + j*4 + kk)*512 + lane*8];
#pragma unroll
      for (int m = 0; m < 4; ++m) {
        f32x4 acc = zero4;
#pragma unroll
        for (int kk = 0; kk < 4; ++kk)
          acc = __builtin_amdgcn_mfma_f32_16x16x32_bf16(afr[m][kk], bfr[kk], acc, 0, 0, 0);
#pragma unroll
        for (int r = 0; r < 4; ++r)
          out_acc[m][j][r] = scl[m][r] * (acc[r] + b3v[j]) + crow[m][r];
      }
    }

    // ---- dump partial into own region, frag-linear (conflict-free b128) ----
    asm volatile("s_waitcnt lgkmcnt(0)" ::: "memory");  // A3 reads done before overwrite
#pragma unroll
    for (int m = 0; m < 4; ++m)
#pragma unroll
      for (int j = 0; j < NJ3; ++j)
        *(f32x4*)&hp[((m*4 + j)*64 + lane)*8] = out_acc[m][j];

    __syncthreads();

    // ---- cross-agent reduce: 1024 f32x4 slots, 512 threads x 2 ----
#pragma unroll
    for (int s2 = 0; s2 < 2; ++s2) {
      int s = tid + s2*512;
      f32x4 sum = zero4;
#pragma unroll
      for (int w = 0; w < 8; ++w) {
        f32x4 v = *(const f32x4*)&hlds[(w*8192) + s*8];
        sum[0] += v[0]; sum[1] += v[1]; sum[2] += v[2]; sum[3] += v[3];
      }
      int mj = s >> 6, ln = s & 63;
      int m = mj >> 2, j = mj & 3;
      int lg2 = ln >> 4, lr2 = ln & 15;
#pragma unroll
      for (int r = 0; r < 4; ++r) {
        int row = row0 + m*16 + lg2*4 + r;
        out[(size_t)row*ADIM + j*16 + lr2] = sum[r] * 0.125f;
      }
    }

    __syncthreads();   // reduce reads done before next pass reuses h
  }
}

extern "C" void kernel_launch(void* const* d_in, const int* in_sizes, int n_in,
                              void* d_out, int out_size, void* d_ws, size_t ws_size,
                              hipStream_t stream)
{
  const float* states = (const float*)d_in[0];
  const float* W1  = (const float*)d_in[1];
  const float* b1  = (const float*)d_in[2];
  const float* W2  = (const float*)d_in[3];
  const float* b2  = (const float*)d_in[4];
  const float* W3  = (const float*)d_in[5];
  const float* b3  = (const float*)d_in[6];
  const float* Ws1 = (const float*)d_in[13];
  const float* bs1 = (const float*)d_in[14];
  const float* Ws2 = (const float*)d_in[15];
  const float* bs2 = (const float*)d_in[16];
  const float* Wc1 = (const float*)d_in[17];
  const float* bc1 = (const float*)d_in[18];
  const float* Wc2 = (const float*)d_in[19];
  const float* bc2 = (const float*)d_in[20];

  unsigned short* wbuf = (unsigned short*)d_ws;
  float* b1e = (float*)((char*)d_ws + (size_t)NAG * WAGENT * 2);

  dim3 pb(256), pg((NAG * WAGENT + 255) / 256);
  prep_weights<<<pg, pb, 0, stream>>>(W1, W2, W3, Wc1, Ws1, b1, bc1, bs1, wbuf, b1e);

  dim3 mb(512), mg(BATCH / 128);   // 256 blocks x 8 waves (agent-parallel)
  qatten_main<<<mg, mb, 0, stream>>>(states, b2, b3, Ws2, bs2, Wc2, bc2,
                                     wbuf, b1e, (float*)d_out);
}

// Round 3
// 67.113 us; speedup vs baseline: 2.4808x; 2.4808x over previous
//
#include <hip/hip_runtime.h>
#include <hip/hip_bf16.h>

#define NAG 8
#define BATCH 32768
#define DDIM 128
#define ADIM 64
#define HDIM 128

#define NJ1 11            // layer1 col tiles: 128 (W1) + 32 (Wc1) + 1 (Ws1) -> 176 cols
#define NJ2 8
#define NJ3 4
#define FB_L1 (NJ1*4)     // 44 frag blocks
#define FB_L2 (NJ2*4)     // 32
#define FB_L3 (NJ3*4)     // 16
#define FB_TOT (FB_L1+FB_L2+FB_L3)  // 92
#define WAGENT (FB_TOT*512)         // 47104 ushort per agent (92KB)

typedef __attribute__((ext_vector_type(8))) short bf16x8;
typedef __attribute__((ext_vector_type(4))) float f32x4;
typedef __attribute__((ext_vector_type(4))) unsigned int u32x4;

static __device__ __forceinline__ unsigned short f2bf(float f) {
  unsigned int u = __builtin_bit_cast(unsigned int, f);
  u += 0x7fffu + ((u >> 16) & 1u);          // RNE (inputs are finite)
  return (unsigned short)(u >> 16);
}

static __device__ __forceinline__ unsigned int cvt_pk_bf16(float a, float b) {
  unsigned int r;
  asm("v_cvt_pk_bf16_f32 %0, %1, %2" : "=v"(r) : "v"(a), "v"(b));
  return r;
}

// ---------------- prep: f32 weights -> bf16 B-fragment-linear layout (proven) ----------------
// frag block fb=(j,kk): 512 bf16; element l*8+t = W[k = kk*32 + (l>>4)*8 + t][col = j*16 + (l&15)]
__global__ void __launch_bounds__(256)
prep_weights(const float* __restrict__ W1, const float* __restrict__ W2,
             const float* __restrict__ W3, const float* __restrict__ Wc1,
             const float* __restrict__ Ws1, const float* __restrict__ b1,
             const float* __restrict__ bc1, const float* __restrict__ bs1,
             unsigned short* __restrict__ wbuf, float* __restrict__ b1e)
{
  int tid = blockIdx.x * 256 + threadIdx.x;
  if (tid < NAG * WAGENT) {
    int agent = tid / WAGENT;
    int rem   = tid % WAGENT;
    int fb = rem >> 9;
    int li = rem & 511;
    int l = li >> 3, t = li & 7;
    int lr = l & 15, lg = l >> 4;
    float v = 0.0f;
    if (fb < FB_L1) {
      int j = fb >> 2, kk = fb & 3;
      int col = j*16 + lr, k = kk*32 + lg*8 + t;
      if (col < 128)       v = W1[((size_t)agent*128 + k)*128 + col];
      else if (col < 160)  v = Wc1[k*32 + (col-128)];
      else if (col == 160) v = Ws1[k];
    } else if (fb < FB_L1 + FB_L2) {
      int f = fb - FB_L1;
      int j = f >> 2, kk = f & 3;
      int col = j*16 + lr, k = kk*32 + lg*8 + t;
      v = W2[((size_t)agent*128 + k)*128 + col];
    } else {
      int f = fb - FB_L1 - FB_L2;
      int j = f >> 2, kk = f & 3;
      int col = j*16 + lr, k = kk*32 + lg*8 + t;
      v = W3[((size_t)agent*128 + k)*64 + col];
    }
    wbuf[tid] = f2bf(v);
  }
  if (tid < NAG * 176) {     // extended layer-1 bias: [b1 | bc1 | bs1 | 0]
    int agent = tid / 176, col = tid % 176;
    float v = 0.0f;
    if (col < 128)       v = b1[agent*128 + col];
    else if (col < 160)  v = bc1[col - 128];
    else if (col == 160) v = bs1[0];
    b1e[tid] = v;
  }
}

// ---------------- main: agent-parallel waves, M=32/wave, 256-thread blocks ----------------
// grid (1024, 2): gid.x = 32-row group, gid.y = agent half (0: agents 0-3, 1: 4-7).
// Wave w handles agent gid.y*4+w. Weights read from global (L2-resident wbuf).
// LDS: 4 x 8KB per-wave h buffer (reused as f32 partial for cross-agent reduce).
// Halves combine via atomicAdd into memset-zeroed out (2 contributors -> deterministic).
__global__ void __launch_bounds__(256, 2)
qatten_main(const float* __restrict__ states,
            const float* __restrict__ b2g, const float* __restrict__ b3g,
            const float* __restrict__ ws2p, const float* __restrict__ bs2p,
            const float* __restrict__ wc2g, const float* __restrict__ bc2p,
            const unsigned short* __restrict__ wbuf,
            const float* __restrict__ b1e,
            float* __restrict__ out)
{
  __shared__ __align__(16) unsigned short hlds[4 * 4096];   // 32 KB

  const int tid  = threadIdx.x;
  const int wave = tid >> 6;
  const int lane = tid & 63;
  const int lr   = lane & 15;
  const int lg   = lane >> 4;
  const int agent = blockIdx.y * 4 + wave;
  const int row0  = blockIdx.x * 32;

  const unsigned short* wag = wbuf + (size_t)agent * WAGENT;
  unsigned short* hp = hlds + wave * 4096;          // this wave's 8KB region

  float b1v[NJ1], b2v[NJ2], b3v[NJ3];
#pragma unroll
  for (int j = 0; j < NJ1; ++j) b1v[j] = b1e[agent*176 + j*16 + lr];
#pragma unroll
  for (int j = 0; j < NJ2; ++j) b2v[j] = b2g[agent*HDIM + j*16 + lr];
#pragma unroll
  for (int j = 0; j < NJ3; ++j) b3v[j] = b3g[agent*ADIM + j*16 + lr];
  const float ws2  = ws2p[0];
  const float bs2v = bs2p[0];
  const float bc2v = bc2p[0];
  const float wc2a = wc2g[lr];
  const float wc2b = wc2g[16 + lr];

  const f32x4 zero4 = {0.f, 0.f, 0.f, 0.f};

  // ---- A1 fragments from global states (f32 -> bf16, 2 m-tiles) ----
  bf16x8 afr[2][4];
  {
    const float* sb = states + ((size_t)agent * BATCH + row0) * DDIM;
#pragma unroll
    for (int m = 0; m < 2; ++m)
#pragma unroll
      for (int kk = 0; kk < 4; ++kk) {
        const float* p = sb + (m*16 + lr)*DDIM + kk*32 + lg*8;
        f32x4 v0 = *(const f32x4*)p;
        f32x4 v1 = *(const f32x4*)(p + 4);
        u32x4 w;
        w[0] = cvt_pk_bf16(v0[0], v0[1]);
        w[1] = cvt_pk_bf16(v0[2], v0[3]);
        w[2] = cvt_pk_bf16(v1[0], v1[1]);
        w[3] = cvt_pk_bf16(v1[2], v1[3]);
        afr[m][kk] = __builtin_bit_cast(bf16x8, w);
      }
  }

  // ---- gate & constraint tiles (j = 8,9,10) ----
  float scl[2][4], crow[2][4];
  {
    f32x4 eacc[3][2];
#pragma unroll
    for (int jx = 0; jx < 3; ++jx) {
      bf16x8 bfr[4];
#pragma unroll
      for (int kk = 0; kk < 4; ++kk)
        bfr[kk] = *(const bf16x8*)&wag[((8+jx)*4 + kk)*512 + lane*8];
#pragma unroll
      for (int m = 0; m < 2; ++m) {
        f32x4 a = zero4;
#pragma unroll
        for (int kk = 0; kk < 4; ++kk)
          a = __builtin_amdgcn_mfma_f32_16x16x32_bf16(afr[m][kk], bfr[kk], a, 0, 0, 0);
        eacc[jx][m] = a;
      }
    }
#pragma unroll
    for (int m = 0; m < 2; ++m) {
#pragma unroll
      for (int r = 0; r < 4; ++r) {
        float c0 = eacc[0][m][r] + b1v[8];  c0 = c0 > 0.f ? c0 : 0.f;
        float c1 = eacc[1][m][r] + b1v[9];  c1 = c1 > 0.f ? c1 : 0.f;
        float cd = c0*wc2a + c1*wc2b;
        cd += __shfl_xor(cd, 1);
        cd += __shfl_xor(cd, 2);
        cd += __shfl_xor(cd, 4);
        cd += __shfl_xor(cd, 8);          // sum over 16 cols within lg-group
        crow[m][r] = cd + bc2v;
        float sp = eacc[2][m][r] + b1v[10];
        sp = __shfl(sp, lane & 48);       // broadcast col-160 (lr==0) value
        sp = sp > 0.f ? sp : 0.f;
        float s = ws2 * sp + bs2v;
        scl[m][r] = 1.f / (1.f + __expf(-s));
      }
    }
  }

  // ---- layer 1 main (j = 0..7) -> h (swizzled row-major [32][128] bf16) ----
#pragma unroll
  for (int j = 0; j < 8; ++j) {
    bf16x8 bfr[4];
#pragma unroll
    for (int kk = 0; kk < 4; ++kk)
      bfr[kk] = *(const bf16x8*)&wag[(j*4 + kk)*512 + lane*8];
#pragma unroll
    for (int m = 0; m < 2; ++m) {
      f32x4 acc = zero4;
#pragma unroll
      for (int kk = 0; kk < 4; ++kk)
        acc = __builtin_amdgcn_mfma_f32_16x16x32_bf16(afr[m][kk], bfr[kk], acc, 0, 0, 0);
#pragma unroll
      for (int r = 0; r < 4; ++r) {
        float hv = acc[r] + b1v[j];
        hv = hv > 0.f ? hv : 0.f;
        int row = m*16 + lg*4 + r;
        int bo = row*256 + (((j*16 + lr)*2) ^ ((row & 7) << 4));   // XOR swizzle
        *(unsigned short*)((char*)hp + bo) = f2bf(hv);
      }
    }
  }

  asm volatile("s_waitcnt lgkmcnt(0)" ::: "memory");
  // ---- A2 fragments from own h region ----
#pragma unroll
  for (int m = 0; m < 2; ++m)
#pragma unroll
    for (int kk = 0; kk < 4; ++kk) {
      int row = m*16 + lr;
      int bo = row*256 + ((kk*64 + lg*16) ^ ((row & 7) << 4));
      afr[m][kk] = *(const bf16x8*)((char*)hp + bo);
    }

  // ---- layer 2 (j = 0..7) ----
#pragma unroll
  for (int j = 0; j < 8; ++j) {
    bf16x8 bfr[4];
#pragma unroll
    for (int kk = 0; kk < 4; ++kk)
      bfr[kk] = *(const bf16x8*)&wag[(FB_L1 + j*4 + kk)*512 + lane*8];
#pragma unroll
    for (int m = 0; m < 2; ++m) {
      f32x4 acc = zero4;
#pragma unroll
      for (int kk = 0; kk < 4; ++kk)
        acc = __builtin_amdgcn_mfma_f32_16x16x32_bf16(afr[m][kk], bfr[kk], acc, 0, 0, 0);
#pragma unroll
      for (int r = 0; r < 4; ++r) {
        float hv = acc[r] + b2v[j];
        hv = hv > 0.f ? hv : 0.f;
        int row = m*16 + lg*4 + r;
        int bo = row*256 + (((j*16 + lr)*2) ^ ((row & 7) << 4));
        *(unsigned short*)((char*)hp + bo) = f2bf(hv);   // overwrite h1
      }
    }
  }

  asm volatile("s_waitcnt lgkmcnt(0)" ::: "memory");
  // ---- A3 fragments from h2 ----
#pragma unroll
  for (int m = 0; m < 2; ++m)
#pragma unroll
    for (int kk = 0; kk < 4; ++kk) {
      int row = m*16 + lr;
      int bo = row*256 + ((kk*64 + lg*16) ^ ((row & 7) << 4));
      afr[m][kk] = *(const bf16x8*)((char*)hp + bo);
    }

  // ---- layer 3 (q), gated, + c folded in ----
  f32x4 out_acc[2][NJ3];
#pragma unroll
  for (int j = 0; j < NJ3; ++j) {
    bf16x8 bfr[4];
#pragma unroll
    for (int kk = 0; kk < 4; ++kk)
      bfr[kk] = *(const bf16x8*)&wag[(FB_L1 + FB_L2 + j*4 + kk)*512 + lane*8];
#pragma unroll
    for (int m = 0; m < 2; ++m) {
      f32x4 acc = zero4;
#pragma unroll
      for (int kk = 0; kk < 4; ++kk)
        acc = __builtin_amdgcn_mfma_f32_16x16x32_bf16(afr[m][kk], bfr[kk], acc, 0, 0, 0);
#pragma unroll
      for (int r = 0; r < 4; ++r)
        out_acc[m][j][r] = scl[m][r] * (acc[r] + b3v[j]) + crow[m][r];
    }
  }

  // ---- dump partial into own region, frag-linear (conflict-free b128) ----
  asm volatile("s_waitcnt lgkmcnt(0)" ::: "memory");  // A3 reads done before overwrite
#pragma unroll
  for (int m = 0; m < 2; ++m)
#pragma unroll
    for (int j = 0; j < NJ3; ++j)
      *(f32x4*)&hp[((m*4 + j)*64 + lane)*8] = out_acc[m][j];

  __syncthreads();

  // ---- cross-wave (4 agents) reduce + atomic combine of the two halves ----
#pragma unroll
  for (int s2 = 0; s2 < 2; ++s2) {
    int s = tid + s2*256;                 // 512 slots of f32x4
    f32x4 sum = zero4;
#pragma unroll
    for (int w = 0; w < 4; ++w) {
      f32x4 v = *(const f32x4*)&hlds[(w*4096) + s*8];
      sum[0] += v[0]; sum[1] += v[1]; sum[2] += v[2]; sum[3] += v[3];
    }
    int mj = s >> 6, ln = s & 63;
    int m = mj >> 2, j = mj & 3;
    int lg2 = ln >> 4, lr2 = ln & 15;
#pragma unroll
    for (int r = 0; r < 4; ++r) {
      int row = row0 + m*16 + lg2*4 + r;
      atomicAdd(&out[(size_t)row*ADIM + j*16 + lr2], sum[r] * 0.125f);
    }
  }
}

extern "C" void kernel_launch(void* const* d_in, const int* in_sizes, int n_in,
                              void* d_out, int out_size, void* d_ws, size_t ws_size,
                              hipStream_t stream)
{
  const float* states = (const float*)d_in[0];
  const float* W1  = (const float*)d_in[1];
  const float* b1  = (const float*)d_in[2];
  const float* W2  = (const float*)d_in[3];
  const float* b2  = (const float*)d_in[4];
  const float* W3  = (const float*)d_in[5];
  const float* b3  = (const float*)d_in[6];
  const float* Ws1 = (const float*)d_in[13];
  const float* bs1 = (const float*)d_in[14];
  const float* Ws2 = (const float*)d_in[15];
  const float* bs2 = (const float*)d_in[16];
  const float* Wc1 = (const float*)d_in[17];
  const float* bc1 = (const float*)d_in[18];
  const float* Wc2 = (const float*)d_in[19];
  const float* bc2 = (const float*)d_in[20];

  unsigned short* wbuf = (unsigned short*)d_ws;
  float* b1e = (float*)((char*)d_ws + (size_t)NAG * WAGENT * 2);

  hipMemsetAsync(d_out, 0, (size_t)out_size * sizeof(float), stream);

  dim3 pb(256), pg((NAG * WAGENT + 255) / 256);
  prep_weights<<<pg, pb, 0, stream>>>(W1, W2, W3, Wc1, Ws1, b1, bc1, bs1, wbuf, b1e);

  dim3 mb(256), mg(BATCH / 32, 2);   // 1024 row-groups x 2 agent halves
  qatten_main<<<mg, mb, 0, stream>>>(states, b2, b3, Ws2, bs2, Wc2, bc2,
                                     wbuf, b1e, (float*)d_out);
}